// Round 1
// baseline (591.879 us; speedup 1.0000x reference)
//
#include <hip/hip_runtime.h>
#include <math.h>

#define BATCH 16384
#define NSETS 1024
#define NCLS  128
#define ALPHA 0.001f
#define BETA  0.001f

// GEMM tile config: 128x128 block tile, BK=32, 256 threads, 8x8 per thread
#define BM 128
#define BN 128
#define BK 32
#define TM 8
#define TN 8

__device__ __forceinline__ float block_reduce_sum(float v, float* sm) {
    #pragma unroll
    for (int off = 32; off > 0; off >>= 1) v += __shfl_down(v, off, 64);
    const int lane = threadIdx.x & 63;
    const int wid  = threadIdx.x >> 6;
    if (lane == 0) sm[wid] = v;
    __syncthreads();
    const int nw = blockDim.x >> 6;
    v = (threadIdx.x < nw) ? sm[threadIdx.x] : 0.0f;
    if (wid == 0) {
        #pragma unroll
        for (int off = 32; off > 0; off >>= 1) v += __shfl_down(v, off, 64);
    }
    return v;  // valid in thread 0
}

// -------- BCE: -mean(t*log(p) + (1-t)*log1p(-p)), t = membership[idx[b], s]
__global__ __launch_bounds__(256)
void bce_kernel(const float* __restrict__ pred,
                const float* __restrict__ membership,
                const int*   __restrict__ tidx,
                float*       __restrict__ ws) {
    __shared__ float sm[4];
    const int N4 = BATCH * NSETS / 4;
    const float eps = 1e-7f;
    const float hi  = 1.0f - 1e-7f;
    float acc = 0.0f;
    for (int i = blockIdx.x * blockDim.x + threadIdx.x; i < N4;
         i += gridDim.x * blockDim.x) {
        const int e  = i << 2;          // flat element index (fits in int)
        const int b  = e >> 10;         // /1024
        const int s4 = (e & 1023) >> 2; // float4 index within row
        const float4 p4 = ((const float4*)pred)[i];
        const int cls   = tidx[b];
        const float4 t4 = ((const float4*)membership)[(cls << 8) + s4];
        const float ps[4] = {p4.x, p4.y, p4.z, p4.w};
        const float ts[4] = {t4.x, t4.y, t4.z, t4.w};
        #pragma unroll
        for (int j = 0; j < 4; j++) {
            const float p = fminf(fmaxf(ps[j], eps), hi);
            acc += (ts[j] > 0.5f) ? logf(p) : log1pf(-p);
        }
    }
    const float tot = block_reduce_sum(acc, sm);
    if (threadIdx.x == 0) atomicAdd(&ws[0], tot);
}

// -------- masses[b,s] = sum_k p[b,k] * moebius[s,k]; fused relu(-m) sum and row sums
__global__ __launch_bounds__(256)
void masses_kernel(const float* __restrict__ A,   // pred [BATCH, NSETS]
                   const float* __restrict__ Bm,  // moebius [NSETS, NSETS]
                   float*       __restrict__ ws) {
    __shared__ float As[BK][BM];    // transposed: [k][m]
    __shared__ float Bs[BK][BN];    // transposed: [k][n]
    __shared__ float rowacc[BM];
    __shared__ float sm[4];

    const int tid = threadIdx.x;
    const int tx  = tid & 15;   // n-dim thread coord
    const int ty  = tid >> 4;   // m-dim thread coord
    const int m0  = blockIdx.y * BM;
    const int n0  = blockIdx.x * BN;

    if (tid < BM) rowacc[tid] = 0.0f;

    float acc[TM][TN];
    #pragma unroll
    for (int i = 0; i < TM; i++)
        #pragma unroll
        for (int j = 0; j < TN; j++) acc[i][j] = 0.0f;

    const int lr = tid >> 3;         // 0..31 row within 32-row load slab
    const int lc = (tid & 7) << 2;   // 0,4,...,28 col (float4)

    for (int k0 = 0; k0 < NSETS; k0 += BK) {
        #pragma unroll
        for (int i = 0; i < 4; i++) {
            const int r = lr + (i << 5);
            const float4 va = *(const float4*)(A  + (size_t)(m0 + r) * NSETS + k0 + lc);
            As[lc + 0][r] = va.x; As[lc + 1][r] = va.y;
            As[lc + 2][r] = va.z; As[lc + 3][r] = va.w;
            const float4 vb = *(const float4*)(Bm + (size_t)(n0 + r) * NSETS + k0 + lc);
            Bs[lc + 0][r] = vb.x; Bs[lc + 1][r] = vb.y;
            Bs[lc + 2][r] = vb.z; Bs[lc + 3][r] = vb.w;
        }
        __syncthreads();
        #pragma unroll
        for (int kk = 0; kk < BK; kk++) {
            float a[TM], b[TN];
            #pragma unroll
            for (int i = 0; i < TM; i++) a[i] = As[kk][ty * TM + i];
            #pragma unroll
            for (int j = 0; j < TN; j++) b[j] = Bs[kk][tx * TN + j];
            #pragma unroll
            for (int i = 0; i < TM; i++)
                #pragma unroll
                for (int j = 0; j < TN; j++) acc[i][j] += a[i] * b[j];
        }
        __syncthreads();
    }

    // Fused epilogue: mr partial + per-row sums (never materialize masses)
    float mrpart = 0.0f;
    float rpart[TM];
    #pragma unroll
    for (int i = 0; i < TM; i++) rpart[i] = 0.0f;
    #pragma unroll
    for (int i = 0; i < TM; i++)
        #pragma unroll
        for (int j = 0; j < TN; j++) {
            const float m = acc[i][j];
            mrpart   += fmaxf(-m, 0.0f);
            rpart[i] += m;
        }
    #pragma unroll
    for (int i = 0; i < TM; i++) atomicAdd(&rowacc[ty * TM + i], rpart[i]);

    const float mrtot = block_reduce_sum(mrpart, sm);  // contains a barrier
    if (tid == 0) atomicAdd(&ws[1], mrtot);
    __syncthreads();
    if (tid < BM) atomicAdd(&ws[2 + m0 + tid], rowacc[tid]);
}

// -------- finalize: ms = mean(|rowsum - 1|); combine all losses
__global__ __launch_bounds__(256)
void finalize_kernel(const float* __restrict__ ws, float* __restrict__ out) {
    __shared__ float sm[4];
    float s = 0.0f;
    for (int b = threadIdx.x; b < BATCH; b += 256)
        s += fabsf(ws[2 + b] - 1.0f);
    const float mssum = block_reduce_sum(s, sm);
    if (threadIdx.x == 0) {
        const float inv = 1.0f / ((float)BATCH * (float)NSETS);
        const float bce = -ws[0] * inv;
        const float mr  =  ws[1] * inv;
        const float ms  =  mssum / (float)BATCH;
        out[0] = bce + ALPHA * mr + BETA * ms;
        out[1] = bce;
        out[2] = mr;
        out[3] = ms;
    }
}

extern "C" void kernel_launch(void* const* d_in, const int* in_sizes, int n_in,
                              void* d_out, int out_size, void* d_ws, size_t ws_size,
                              hipStream_t stream) {
    const float* pred       = (const float*)d_in[0];
    const float* membership = (const float*)d_in[1];
    const float* moebius    = (const float*)d_in[2];
    const int*   tidx       = (const int*)d_in[3];
    float* out = (float*)d_out;
    float* ws  = (float*)d_ws;

    // zero accumulators: ws[0]=bce_sum, ws[1]=mr_sum, ws[2..2+BATCH)=row sums
    hipMemsetAsync(d_ws, 0, (2 + BATCH) * sizeof(float), stream);

    bce_kernel<<<2048, 256, 0, stream>>>(pred, membership, tidx, ws);
    masses_kernel<<<dim3(NSETS / BN, BATCH / BM), 256, 0, stream>>>(pred, moebius, ws);
    finalize_kernel<<<1, 256, 0, stream>>>(ws, out);
}

// Round 2
// 209.673 us; speedup vs baseline: 2.8229x; 2.8229x over previous
//
#include <hip/hip_runtime.h>
#include <math.h>

#define BATCH 16384
#define NSETS 1024
#define ALPHA 0.001f
#define BETA  0.001f

// MFMA GEMM tile: 128x128 block, BK=32, 256 threads (4 waves, 2x2 wave grid,
// each wave 64x64 = 4x4 grid of 16x16x32 bf16 MFMA tiles)
#define BM 128
#define BN 128
#define BK 32

typedef __attribute__((ext_vector_type(4))) float f32x4;
typedef __attribute__((ext_vector_type(8))) __bf16 bf16x8;

// ws layout (bytes):
//   [0]                : bce_sum (float)
//   [4]                : mr_sum (float)
//   [8 .. 8+4*BATCH)   : per-row mass sums (float)
//   [131072 .. )       : pred_bf16  (BATCH*NSETS ushort = 33.5 MB)
//   [131072+33554432..): moeb_bf16  (NSETS*NSETS ushort = 2 MB)
#define WS_PREDBF_OFF 131072
#define WS_MOEBBF_OFF (131072 + BATCH * NSETS * 2)

__device__ __forceinline__ unsigned short f2bf(float x) {
    unsigned int u = __builtin_bit_cast(unsigned int, x);
    u = (u + 0x7FFFu + ((u >> 16) & 1u)) >> 16;   // RNE (no NaN inputs here)
    return (unsigned short)u;
}

__device__ __forceinline__ void gld16(const void* g, void* l) {
    __builtin_amdgcn_global_load_lds(
        (const __attribute__((address_space(1))) unsigned int*)g,
        (__attribute__((address_space(3))) unsigned int*)l, 16, 0, 0);
}

__device__ __forceinline__ float block_reduce_sum(float v, float* sm) {
    #pragma unroll
    for (int off = 32; off > 0; off >>= 1) v += __shfl_down(v, off, 64);
    const int lane = threadIdx.x & 63;
    const int wid  = threadIdx.x >> 6;
    if (lane == 0) sm[wid] = v;
    __syncthreads();
    const int nw = blockDim.x >> 6;
    v = (threadIdx.x < nw) ? sm[threadIdx.x] : 0.0f;
    if (wid == 0) {
        #pragma unroll
        for (int off = 32; off > 0; off >>= 1) v += __shfl_down(v, off, 64);
    }
    return v;  // valid in thread 0
}

// -------- BCE (+ fused fp32 -> bf16 conversion of clipped pred)
__global__ __launch_bounds__(256)
void bce_convert_kernel(const float* __restrict__ pred,
                        const float* __restrict__ membership,
                        const int*   __restrict__ tidx,
                        float*       __restrict__ ws,
                        unsigned short* __restrict__ pred_bf) {
    __shared__ float sm[4];
    const int N4 = BATCH * NSETS / 4;
    const float eps = 1e-7f;
    const float hi  = 1.0f - 1e-7f;
    float acc = 0.0f;
    for (int i = blockIdx.x * blockDim.x + threadIdx.x; i < N4;
         i += gridDim.x * blockDim.x) {
        const int e  = i << 2;
        const int b  = e >> 10;
        const int s4 = (e & 1023) >> 2;
        const float4 p4 = ((const float4*)pred)[i];
        const int cls   = tidx[b];
        const float4 t4 = ((const float4*)membership)[(cls << 8) + s4];
        float cp[4];
        cp[0] = fminf(fmaxf(p4.x, eps), hi);
        cp[1] = fminf(fmaxf(p4.y, eps), hi);
        cp[2] = fminf(fmaxf(p4.z, eps), hi);
        cp[3] = fminf(fmaxf(p4.w, eps), hi);
        ushort4 u;
        u.x = f2bf(cp[0]); u.y = f2bf(cp[1]); u.z = f2bf(cp[2]); u.w = f2bf(cp[3]);
        ((ushort4*)pred_bf)[i] = u;
        const float ts[4] = {t4.x, t4.y, t4.z, t4.w};
        #pragma unroll
        for (int j = 0; j < 4; j++) {
            const float lp = __logf(cp[j]);
            const float lq = __logf(1.0f - cp[j]);
            acc += (ts[j] > 0.5f) ? lp : lq;
        }
    }
    const float tot = block_reduce_sum(acc, sm);
    if (threadIdx.x == 0) atomicAdd(&ws[0], tot);
}

// -------- moebius fp32 -> bf16
__global__ __launch_bounds__(256)
void convert_moeb_kernel(const float* __restrict__ src,
                         unsigned short* __restrict__ dst) {
    const int i = blockIdx.x * blockDim.x + threadIdx.x;  // exactly NSETS*NSETS/4 threads
    const float4 v = ((const float4*)src)[i];
    ushort4 u;
    u.x = f2bf(v.x); u.y = f2bf(v.y); u.z = f2bf(v.z); u.w = f2bf(v.w);
    ((ushort4*)dst)[i] = u;
}

// -------- masses = p_bf16 @ moeb_bf16^T via MFMA; fused relu(-m) and row sums
__global__ __launch_bounds__(256)
void masses_mfma_kernel(const unsigned short* __restrict__ A,   // pred_bf [BATCH, NSETS]
                        const unsigned short* __restrict__ Bm,  // moeb_bf [NSETS, NSETS]
                        float* __restrict__ ws) {
    __shared__ __align__(16) unsigned short Alds[BM * BK];  // [m][k], k contiguous
    __shared__ __align__(16) unsigned short Blds[BN * BK];  // [n][k], k contiguous
    __shared__ float rowacc[BM];
    __shared__ float sm[4];

    const int tid  = threadIdx.x;
    const int lane = tid & 63;
    const int w    = tid >> 6;
    const int wm   = w >> 1;         // wave m-quadrant (0/1)
    const int wn   = w & 1;          // wave n-quadrant (0/1)
    const int lr   = lane & 15;
    const int q    = lane >> 4;      // quad 0..3
    const int m0   = blockIdx.y * BM;
    const int n0   = blockIdx.x * BN;

    if (tid < BM) rowacc[tid] = 0.0f;

    f32x4 acc[4][4];
    #pragma unroll
    for (int i = 0; i < 4; i++)
        #pragma unroll
        for (int j = 0; j < 4; j++) acc[i][j] = (f32x4){0.f, 0.f, 0.f, 0.f};

    // staging: 512 chunks of 16B per tile; thread t covers chunk t and t+256.
    // chunk c -> row c>>2, k-subchunk c&3 (8 bf16 each)
    const unsigned short* Ag0 = A  + (size_t)(m0 + (tid >> 2)) * NSETS + (tid & 3) * 8;
    const unsigned short* Bg0 = Bm + (size_t)(n0 + (tid >> 2)) * NSETS + (tid & 3) * 8;
    unsigned short* lA0 = &Alds[tid * 8];
    unsigned short* lA1 = &Alds[(tid + 256) * 8];
    unsigned short* lB0 = &Blds[tid * 8];
    unsigned short* lB1 = &Blds[(tid + 256) * 8];
    const size_t rowskip = (size_t)64 * NSETS;  // +64 rows for second chunk

    for (int k0 = 0; k0 < NSETS; k0 += BK) {
        gld16(Ag0 + k0, lA0);
        gld16(Ag0 + k0 + rowskip, lA1);
        gld16(Bg0 + k0, lB0);
        gld16(Bg0 + k0 + rowskip, lB1);
        __syncthreads();

        bf16x8 a[4], b[4];
        #pragma unroll
        for (int mi = 0; mi < 4; mi++)
            a[mi] = *(const bf16x8*)&Alds[(wm * 64 + mi * 16 + lr) * BK + q * 8];
        #pragma unroll
        for (int ni = 0; ni < 4; ni++)
            b[ni] = *(const bf16x8*)&Blds[(wn * 64 + ni * 16 + lr) * BK + q * 8];
        #pragma unroll
        for (int mi = 0; mi < 4; mi++)
            #pragma unroll
            for (int ni = 0; ni < 4; ni++)
                acc[mi][ni] = __builtin_amdgcn_mfma_f32_16x16x32_bf16(
                    a[mi], b[ni], acc[mi][ni], 0, 0, 0);
        __syncthreads();
    }

    // Epilogue. C/D layout: col = lane&15, row_in_tile = q*4 + r
    float mrpart = 0.0f;
    float rs[4][4];  // [mi][r]
    #pragma unroll
    for (int mi = 0; mi < 4; mi++)
        #pragma unroll
        for (int r = 0; r < 4; r++) rs[mi][r] = 0.0f;
    #pragma unroll
    for (int mi = 0; mi < 4; mi++)
        #pragma unroll
        for (int ni = 0; ni < 4; ni++)
            #pragma unroll
            for (int r = 0; r < 4; r++) {
                const float m = acc[mi][ni][r];
                mrpart     += fmaxf(-m, 0.0f);
                rs[mi][r]  += m;
            }
    // reduce row sums across the 16 cols held by lanes lr=0..15 of each quad
    #pragma unroll
    for (int mi = 0; mi < 4; mi++)
        #pragma unroll
        for (int r = 0; r < 4; r++) {
            float v = rs[mi][r];
            #pragma unroll
            for (int off = 1; off < 16; off <<= 1) v += __shfl_xor(v, off, 16);
            if (lr == 0)
                atomicAdd(&rowacc[wm * 64 + mi * 16 + q * 4 + r], v);
        }

    const float mrtot = block_reduce_sum(mrpart, sm);  // has a barrier inside
    if (tid == 0) atomicAdd(&ws[1], mrtot);
    __syncthreads();
    if (tid < BM) atomicAdd(&ws[2 + m0 + tid], rowacc[tid]);
}

// -------- finalize: ms = mean(|rowsum - 1|); combine all losses
__global__ __launch_bounds__(256)
void finalize_kernel(const float* __restrict__ ws, float* __restrict__ out) {
    __shared__ float sm[4];
    float s = 0.0f;
    for (int b = threadIdx.x; b < BATCH; b += 256)
        s += fabsf(ws[2 + b] - 1.0f);
    const float mssum = block_reduce_sum(s, sm);
    if (threadIdx.x == 0) {
        const float inv = 1.0f / ((float)BATCH * (float)NSETS);
        const float bce = -ws[0] * inv;
        const float mr  =  ws[1] * inv;
        const float ms  =  mssum / (float)BATCH;
        out[0] = bce + ALPHA * mr + BETA * ms;
        out[1] = bce;
        out[2] = mr;
        out[3] = ms;
    }
}

extern "C" void kernel_launch(void* const* d_in, const int* in_sizes, int n_in,
                              void* d_out, int out_size, void* d_ws, size_t ws_size,
                              hipStream_t stream) {
    const float* pred       = (const float*)d_in[0];
    const float* membership = (const float*)d_in[1];
    const float* moebius    = (const float*)d_in[2];
    const int*   tidx       = (const int*)d_in[3];
    float* out = (float*)d_out;
    float* ws  = (float*)d_ws;
    unsigned short* pred_bf = (unsigned short*)((char*)d_ws + WS_PREDBF_OFF);
    unsigned short* moeb_bf = (unsigned short*)((char*)d_ws + WS_MOEBBF_OFF);

    // zero accumulators: ws[0]=bce_sum, ws[1]=mr_sum, ws[2..2+BATCH)=row sums
    hipMemsetAsync(d_ws, 0, (2 + BATCH) * sizeof(float), stream);

    convert_moeb_kernel<<<NSETS * NSETS / 4 / 256, 256, 0, stream>>>(moebius, moeb_bf);
    bce_convert_kernel<<<2048, 256, 0, stream>>>(pred, membership, tidx, ws, pred_bf);
    masses_mfma_kernel<<<dim3(NSETS / BN, BATCH / BM), 256, 0, stream>>>(pred_bf, moeb_bf, ws);
    finalize_kernel<<<1, 256, 0, stream>>>(ws, out);
}

// Round 3
// 181.428 us; speedup vs baseline: 3.2623x; 1.1557x over previous
//
#include <hip/hip_runtime.h>
#include <math.h>

#define BATCH 16384
#define NSETS 1024
#define ALPHA 0.001f
#define BETA  0.001f

// MFMA GEMM tile: 128x128 block, BK=64, 256 threads (4 waves, 2x2 wave grid,
// each wave 64x64 = 4x4 grid of 16x16x32 bf16 MFMA tiles, 2 k-steps per iter)
#define BM 128
#define BN 128
#define BK 64

typedef __attribute__((ext_vector_type(4))) float f32x4;
typedef __attribute__((ext_vector_type(8))) __bf16 bf16x8;

// ws layout (bytes):
//   [0]  bce_sum   [4] mr_sum   [16 .. 16+4*BATCH) row sums (16B-aligned)
//   [131072 ..)            pred_bf16 (BATCH*NSETS ushort = 33.5 MB)
//   [131072 + 33554432 ..) moeb_bf16 (NSETS*NSETS ushort = 2 MB)
#define WS_PREDBF_OFF 131072
#define WS_MOEBBF_OFF (131072 + BATCH * NSETS * 2)
#define ROWSUM_OFF 4   // float index

__device__ __forceinline__ unsigned short f2bf(float x) {
    unsigned int u = __builtin_bit_cast(unsigned int, x);
    u = (u + 0x7FFFu + ((u >> 16) & 1u)) >> 16;   // RNE (no NaN inputs here)
    return (unsigned short)u;
}

__device__ __forceinline__ void gld16(const void* g, void* l) {
    __builtin_amdgcn_global_load_lds(
        (const __attribute__((address_space(1))) unsigned int*)g,
        (__attribute__((address_space(3))) unsigned int*)l, 16, 0, 0);
}

__device__ __forceinline__ float block_reduce_sum(float v, float* sm) {
    #pragma unroll
    for (int off = 32; off > 0; off >>= 1) v += __shfl_down(v, off, 64);
    const int lane = threadIdx.x & 63;
    const int wid  = threadIdx.x >> 6;
    if (lane == 0) sm[wid] = v;
    __syncthreads();
    const int nw = blockDim.x >> 6;
    v = (threadIdx.x < nw) ? sm[threadIdx.x] : 0.0f;
    if (wid == 0) {
        #pragma unroll
        for (int off = 32; off > 0; off >>= 1) v += __shfl_down(v, off, 64);
    }
    return v;  // valid in thread 0
}

// -------- BCE (+ fused pred->bf16 convert; blocks >= 2048 convert moebius)
__global__ __launch_bounds__(256)
void bce_convert_kernel(const float* __restrict__ pred,
                        const float* __restrict__ membership,
                        const int*   __restrict__ tidx,
                        const float* __restrict__ moeb,
                        float*       __restrict__ ws,
                        unsigned short* __restrict__ pred_bf,
                        unsigned short* __restrict__ moeb_bf) {
    if (blockIdx.x >= 2048) {   // moebius fp32->bf16: 64 blocks, 16 float4/thread
        const int base = (blockIdx.x - 2048) * 4096 + threadIdx.x;
        #pragma unroll
        for (int k = 0; k < 16; k++) {
            const int i = base + k * 256;
            const float4 v = ((const float4*)moeb)[i];
            ushort4 u;
            u.x = f2bf(v.x); u.y = f2bf(v.y); u.z = f2bf(v.z); u.w = f2bf(v.w);
            ((ushort4*)moeb_bf)[i] = u;
        }
        return;
    }
    __shared__ float sm[4];
    const int N4 = BATCH * NSETS / 4;
    const float eps = 1e-7f;
    const float hi  = 1.0f - 1e-7f;
    float acc = 0.0f;
    for (int i = blockIdx.x * 256 + threadIdx.x; i < N4; i += 2048 * 256) {
        const int e  = i << 2;
        const int b  = e >> 10;
        const int s4 = (e & 1023) >> 2;
        const float4 p4 = ((const float4*)pred)[i];
        const int cls   = tidx[b];
        const float4 t4 = ((const float4*)membership)[(cls << 8) + s4];
        float cp[4];
        cp[0] = fminf(fmaxf(p4.x, eps), hi);
        cp[1] = fminf(fmaxf(p4.y, eps), hi);
        cp[2] = fminf(fmaxf(p4.z, eps), hi);
        cp[3] = fminf(fmaxf(p4.w, eps), hi);
        ushort4 u;
        u.x = f2bf(cp[0]); u.y = f2bf(cp[1]); u.z = f2bf(cp[2]); u.w = f2bf(cp[3]);
        ((ushort4*)pred_bf)[i] = u;
        const float ts[4] = {t4.x, t4.y, t4.z, t4.w};
        #pragma unroll
        for (int j = 0; j < 4; j++) {
            const float lp = __logf(cp[j]);
            const float lq = __logf(1.0f - cp[j]);
            acc += (ts[j] > 0.5f) ? lp : lq;
        }
    }
    const float tot = block_reduce_sum(acc, sm);
    if (threadIdx.x == 0) atomicAdd(&ws[0], tot);
}

// -------- masses = p_bf16 @ moeb_bf16^T via MFMA; fused relu(-m) and row sums
// LDS layout: 16B chunk (row r, k-subchunk k8) stored at slot 8*r + (k8^(r&7))
// (global-side swizzle; gld16 forces LDS dest = base + lane*16, so banks are
// balanced by permuting the GLOBAL source instead: 8 phases x 8 lanes = b128 min)
__global__ __launch_bounds__(256)
void masses_mfma_kernel(const unsigned short* __restrict__ A,   // pred_bf [BATCH, NSETS]
                        const unsigned short* __restrict__ Bm,  // moeb_bf [NSETS, NSETS]
                        float* __restrict__ ws) {
    __shared__ __align__(16) unsigned short Alds[BM * BK];  // 16 KB
    __shared__ __align__(16) unsigned short Blds[BN * BK];  // 16 KB
    __shared__ float rowacc[BM];
    __shared__ float sm[4];

    const int tid  = threadIdx.x;
    const int lane = tid & 63;
    const int w    = tid >> 6;
    const int wm   = w >> 1;
    const int wn   = w & 1;
    const int lr   = lane & 15;
    const int q    = lane >> 4;
    const int m0   = blockIdx.y * BM;
    const int n0   = blockIdx.x * BN;

    if (tid < BM) rowacc[tid] = 0.0f;

    f32x4 acc[4][4];
    #pragma unroll
    for (int i = 0; i < 4; i++)
        #pragma unroll
        for (int j = 0; j < 4; j++) acc[i][j] = (f32x4){0.f, 0.f, 0.f, 0.f};

    // staging: 1024 chunks of 16B per tile; thread t covers slots t+j*256.
    // slot s -> row r=s>>3, stored k8' = s&7, global k8 = k8' ^ (r&7)
    size_t aoff[4], boff[4];
    unsigned short *lA[4], *lB[4];
    #pragma unroll
    for (int j = 0; j < 4; j++) {
        const int s   = tid + j * 256;
        const int r   = s >> 3;
        const int gk8 = (s & 7) ^ (r & 7);
        aoff[j] = (size_t)(m0 + r) * NSETS + gk8 * 8;
        boff[j] = (size_t)(n0 + r) * NSETS + gk8 * 8;
        lA[j] = &Alds[s * 8];
        lB[j] = &Blds[s * 8];
    }
    const int sw = lr & 7;  // fragment-read swizzle term

    for (int k0 = 0; k0 < NSETS; k0 += BK) {
        #pragma unroll
        for (int j = 0; j < 4; j++) {
            gld16(A  + aoff[j] + k0, lA[j]);
            gld16(Bm + boff[j] + k0, lB[j]);
        }
        __syncthreads();

        #pragma unroll
        for (int h = 0; h < 2; h++) {
            bf16x8 a[4], b[4];
            const int hq = h * 4 + q;
            #pragma unroll
            for (int mi = 0; mi < 4; mi++)
                a[mi] = *(const bf16x8*)&Alds[(wm * 64 + mi * 16 + lr) * BK + 8 * (hq ^ sw)];
            #pragma unroll
            for (int ni = 0; ni < 4; ni++)
                b[ni] = *(const bf16x8*)&Blds[(wn * 64 + ni * 16 + lr) * BK + 8 * (hq ^ sw)];
            #pragma unroll
            for (int mi = 0; mi < 4; mi++)
                #pragma unroll
                for (int ni = 0; ni < 4; ni++)
                    acc[mi][ni] = __builtin_amdgcn_mfma_f32_16x16x32_bf16(
                        a[mi], b[ni], acc[mi][ni], 0, 0, 0);
        }
        __syncthreads();
    }

    // Epilogue. C/D layout: col = lane&15, row_in_tile = q*4 + r
    float mrpart = 0.0f;
    float rs[4][4];
    #pragma unroll
    for (int mi = 0; mi < 4; mi++)
        #pragma unroll
        for (int r = 0; r < 4; r++) rs[mi][r] = 0.0f;
    #pragma unroll
    for (int mi = 0; mi < 4; mi++)
        #pragma unroll
        for (int ni = 0; ni < 4; ni++)
            #pragma unroll
            for (int r = 0; r < 4; r++) {
                const float m = acc[mi][ni][r];
                mrpart    += fmaxf(-m, 0.0f);
                rs[mi][r] += m;
            }
    #pragma unroll
    for (int mi = 0; mi < 4; mi++)
        #pragma unroll
        for (int r = 0; r < 4; r++) {
            float v = rs[mi][r];
            #pragma unroll
            for (int off = 1; off < 16; off <<= 1) v += __shfl_xor(v, off, 16);
            if (lr == 0)
                atomicAdd(&rowacc[wm * 64 + mi * 16 + q * 4 + r], v);
        }

    const float mrtot = block_reduce_sum(mrpart, sm);  // has a barrier inside
    if (tid == 0) atomicAdd(&ws[1], mrtot);
    __syncthreads();
    if (tid < BM) atomicAdd(&ws[ROWSUM_OFF + m0 + tid], rowacc[tid]);
}

// -------- finalize: ms = mean(|rowsum - 1|); combine all losses
__global__ __launch_bounds__(1024)
void finalize_kernel(const float* __restrict__ ws, float* __restrict__ out) {
    __shared__ float sm[16];
    const int tid = threadIdx.x;
    float s = 0.0f;
    #pragma unroll
    for (int k = 0; k < 4; k++) {
        const float4 v = ((const float4*)(ws + ROWSUM_OFF))[tid + k * 1024];
        s += fabsf(v.x - 1.0f) + fabsf(v.y - 1.0f) +
             fabsf(v.z - 1.0f) + fabsf(v.w - 1.0f);
    }
    const float mssum = block_reduce_sum(s, sm);
    if (tid == 0) {
        const float inv = 1.0f / ((float)BATCH * (float)NSETS);
        const float bce = -ws[0] * inv;
        const float mr  =  ws[1] * inv;
        const float ms  =  mssum / (float)BATCH;
        out[0] = bce + ALPHA * mr + BETA * ms;
        out[1] = bce;
        out[2] = mr;
        out[3] = ms;
    }
}

extern "C" void kernel_launch(void* const* d_in, const int* in_sizes, int n_in,
                              void* d_out, int out_size, void* d_ws, size_t ws_size,
                              hipStream_t stream) {
    const float* pred       = (const float*)d_in[0];
    const float* membership = (const float*)d_in[1];
    const float* moebius    = (const float*)d_in[2];
    const int*   tidx       = (const int*)d_in[3];
    float* out = (float*)d_out;
    float* ws  = (float*)d_ws;
    unsigned short* pred_bf = (unsigned short*)((char*)d_ws + WS_PREDBF_OFF);
    unsigned short* moeb_bf = (unsigned short*)((char*)d_ws + WS_MOEBBF_OFF);

    // zero accumulators: ws[0]=bce, ws[1]=mr, ws[4..4+BATCH)=row sums
    hipMemsetAsync(d_ws, 0, (ROWSUM_OFF + BATCH) * sizeof(float), stream);

    bce_convert_kernel<<<2048 + 64, 256, 0, stream>>>(
        pred, membership, tidx, moebius, ws, pred_bf, moeb_bf);
    masses_mfma_kernel<<<dim3(NSETS / BN, BATCH / BM), 256, 0, stream>>>(pred_bf, moeb_bf, ws);
    finalize_kernel<<<1, 1024, 0, stream>>>(ws, out);
}